// Round 15
// baseline (280.160 us; speedup 1.0000x reference)
//
#include <hip/hip_runtime.h>
#include <hip/hip_bf16.h>

// B=4, T=1024, E=512, H=8. Two-pass attention, all matmuls on one GEMM:
//   cast5 -> QK proj (fused dispatch) + Vt (=Wv.x^T) -> S=QK^T*a
//   -> softmax(S-mask) in place -> O=P.V -> out GEMM split-K=8 + reduce(+bias).
// gemm_bt2: C = alpha*A.B^T, 256x128 tile, BK=32, 512 thr / 8 waves (4M x 2N),
// 3-buffer LDS (3 x 24KB = 72KB) -> 2 BLOCKS/CU co-resident (4 waves/SIMD):
// cross-block overlap absorbs barrier/vmcnt stalls (m114/m97 mechanism) --
// the lever 256^2 could never have (128KB LDS + 128-reg acc both forbid it).
// Counted-vmcnt pipeline kept from R12 (proven): stage(t+2) each iter,
// s_waitcnt vmcnt(3) before raw s_barrier (t+1 forced, t+2 in flight).
// REGISTER LAW (R5/R8/R9/R10): 512-thr block, 2nd arg a -> VGPR cap 512/(2a).
// (512,2) -> cap 128; this kernel needs ~126 (acc 64 + frags 32 + ~30). If
// WRITE_SIZE balloons vs 65.5MB -> spill -> revert.
// Fragment-major LDS = conflict-free ds_read_b128 (SQ_LDS_BANK_CONFLICT=0).
// T1 bijective XCD swizzle (all grids % 8 == 0).
// Layouts: Q,K [b,t,h,e] ld 4096; Vt [h*e, b*t]; S/P [b,h,q,k]; O [b,t,h*e].

typedef short bf16x8 __attribute__((ext_vector_type(8)));
typedef float f32x4 __attribute__((ext_vector_type(4)));
typedef unsigned short u16x8 __attribute__((ext_vector_type(8)));

__device__ __forceinline__ unsigned short f2bf(float f) {
  unsigned int u = __float_as_uint(f);
  u += 0x7FFFu + ((u >> 16) & 1u);            // RNE, finite inputs
  return (unsigned short)(u >> 16);
}
__device__ __forceinline__ float bf2f(unsigned short s) {
  return __uint_as_float(((unsigned int)s) << 16);
}

typedef const __attribute__((address_space(1))) unsigned int* gas1_t;
typedef __attribute__((address_space(3))) unsigned int* las3_t;

__device__ __forceinline__ void gload16(const unsigned short* g, unsigned short* l) {
  __builtin_amdgcn_global_load_lds((gas1_t)g, (las3_t)l, 16, 0, 0);
}

__device__ __forceinline__ void store_val(unsigned short* p, float v) { *p = f2bf(v); }
__device__ __forceinline__ void store_val(float* p, float v) { *p = v; }

// ---------------- 256x128-tile BT GEMM, BK=32, 3-buf counted-vmcnt ----------------
// Buffer p at elems [p*12288,+12288): A frags 0..15 at [0,8192) (frag f = tile
// rows f*16+l15, k-chunk lhi*8, slot=lane 16B), B frags 0..7 at [8192,12288).
// Wave w stages A frags {2w,2w+1} + B frag {w} (3 gload16/wave/tile).
template<typename OutT>
__global__ __launch_bounds__(512, 2) void gemm_bt2(
    const unsigned short* __restrict__ A, const unsigned short* __restrict__ B,
    OutT* __restrict__ C,
    int K, int lda, int ldb, int ldc, int zshift,
    long long sAb, long long sAh, long long sBb, long long sBh,
    long long sCb, long long sCh, float alpha)
{
  const int tid  = threadIdx.x;
  const int lane = tid & 63;
  const int wave = tid >> 6;
  const int l15 = lane & 15, lhi = lane >> 4;
  const int wm = wave >> 1, wn = wave & 1;           // 4M x 2N wave grid

  // T1: bijective XCD chunk swizzle (nwg % 8 == 0 for every launch here)
  const int nx = gridDim.x, nxy = gridDim.x * gridDim.y;
  const int nwg = nxy * gridDim.z;
  int flat = blockIdx.x + nx * blockIdx.y + nxy * blockIdx.z;
  flat = (flat & 7) * (nwg >> 3) + (flat >> 3);
  const int bz = flat / nxy;
  const int rem = flat - bz * nxy;
  const int by = rem / nx;
  const int bx = rem - by * nx;

  const int bb = bz >> zshift, hh = bz & ((1 << zshift) - 1);
  const long long m0 = (long long)by * 256;
  const long long n0 = (long long)bx * 128;

  const unsigned short* Ab = A + bb * sAb + hh * sAh;
  const unsigned short* Bb = B + bb * sBb + hh * sBh;

  __shared__ __align__(16) unsigned short lds[36864];  // 72 KB, 3 buffers

  const unsigned short* pA0 = Ab + (size_t)(m0 + (2 * wave) * 16 + l15) * lda + lhi * 8;
  const unsigned short* pA1 = Ab + (size_t)(m0 + (2 * wave + 1) * 16 + l15) * lda + lhi * 8;
  const unsigned short* pB0 = Bb + (size_t)(n0 + wave * 16 + l15) * ldb + lhi * 8;

  // stage K-tile n into buffer p (3 gload16 per wave, 24 KB per block)
  auto stage = [&](int n, int p) {
    unsigned short* dst = lds + p * 12288;
    const int ko = n * 32;
    gload16(pA0 + ko, dst + (2 * wave) * 512);
    gload16(pA1 + ko, dst + (2 * wave + 1) * 512);
    gload16(pB0 + ko, dst + 8192 + wave * 512);
  };

  f32x4 acc[4][4];
#pragma unroll
  for (int m = 0; m < 4; ++m)
#pragma unroll
    for (int n = 0; n < 4; ++n) acc[m][n] = (f32x4){0.f, 0.f, 0.f, 0.f};

  const int nt = K >> 5;                // K-tiles of 32
  // prologue: 2-deep prefetch
  stage(0, 0);
  stage(1, 1);
  asm volatile("s_waitcnt vmcnt(3)" ::: "memory");   // tile 0 landed
  __builtin_amdgcn_sched_barrier(0);
  __builtin_amdgcn_s_barrier();
  __builtin_amdgcn_sched_barrier(0);

  int cur = 0, nx2 = 2;                 // t%3 and (t+2)%3, maintained rotating
  for (int t = 0; t < nt; ++t) {
    const bool pref = (t + 2 < nt);
    if (pref) stage(t + 2, nx2);
    const unsigned short* base = lds + cur * 12288;
    bf16x8 af[4], bf[4];
#pragma unroll
    for (int mf = 0; mf < 4; ++mf)
      af[mf] = *(const bf16x8*)(base + (wm * 4 + mf) * 512 + lane * 8);
#pragma unroll
    for (int nf = 0; nf < 4; ++nf)
      bf[nf] = *(const bf16x8*)(base + 8192 + (wn * 4 + nf) * 512 + lane * 8);
    __builtin_amdgcn_s_setprio(1);
#pragma unroll
    for (int mf = 0; mf < 4; ++mf)
#pragma unroll
      for (int nf = 0; nf < 4; ++nf)
        acc[mf][nf] = __builtin_amdgcn_mfma_f32_16x16x32_bf16(af[mf], bf[nf], acc[mf][nf], 0, 0, 0);
    __builtin_amdgcn_s_setprio(0);
    // counted drain: force tile t+1 complete; t+2's 3 loads stay in flight
    if (pref) asm volatile("s_waitcnt vmcnt(3)" ::: "memory");
    else      asm volatile("s_waitcnt vmcnt(0)" ::: "memory");
    __builtin_amdgcn_sched_barrier(0);
    __builtin_amdgcn_s_barrier();
    __builtin_amdgcn_sched_barrier(0);
    cur = (cur == 2) ? 0 : cur + 1;
    nx2 = (nx2 == 2) ? 0 : nx2 + 1;
  }

  // C/D layout (m89/m91): col = lane&15, row = (lane>>4)*4 + reg
  OutT* Cb = C + bb * sCb + hh * sCh;
#pragma unroll
  for (int mf = 0; mf < 4; ++mf) {
#pragma unroll
    for (int nf = 0; nf < 4; ++nf) {
      const long long col = n0 + wn * 64 + nf * 16 + l15;
#pragma unroll
      for (int r = 0; r < 4; ++r) {
        const long long row = m0 + wm * 64 + mf * 16 + lhi * 4 + r;
        store_val(Cb + (size_t)row * ldc + col, acc[mf][nf][r] * alpha);
      }
    }
  }
}

// ---------------- split-K reduce: out = sum(partials) + bias ----------------
__global__ __launch_bounds__(256) void reduce_kernel(
    const float* __restrict__ P, const float* __restrict__ bias,
    float* __restrict__ out)
{
  const int i = blockIdx.x * 256 + threadIdx.x;      // 0..524287 float4s
  const int col4 = i & 127;
  const float4* p4 = (const float4*)P + i;
  float4 s = p4[0];
#pragma unroll
  for (int z = 1; z < 8; ++z) {
    float4 v = p4[(size_t)z * 524288];
    s.x += v.x; s.y += v.y; s.z += v.z; s.w += v.w;
  }
  float4 b = ((const float4*)bias)[col4];
  s.x += b.x; s.y += b.y; s.z += b.z; s.w += b.w;
  ((float4*)out)[i] = s;
}

// ---------------- fused fp32 -> bf16 cast of all 5 tensors ----------------
__global__ __launch_bounds__(256) void cast5_kernel(
    const float* __restrict__ s0, const float* __restrict__ s1,
    const float* __restrict__ s2, const float* __restrict__ s3,
    const float* __restrict__ s4, unsigned short* __restrict__ dst)
{
  const int seg = blockIdx.x >> 11;
  const int off = (blockIdx.x & 2047) * 256 + threadIdx.x;
  const float* s = s0;
  if (seg == 1) s = s1; else if (seg == 2) s = s2;
  else if (seg == 3) s = s3; else if (seg == 4) s = s4;
  float4 v = ((const float4*)s)[off];
  ushort4 o;
  o.x = f2bf(v.x); o.y = f2bf(v.y); o.z = f2bf(v.z); o.w = f2bf(v.w);
  ((ushort4*)dst)[(size_t)seg * 524288 + off] = o;
}

// ---------------- in-place row softmax over S (bf16), logit = S - mask ----------------
__global__ __launch_bounds__(256) void softmax_kernel(
    unsigned short* __restrict__ S, const float* __restrict__ mask)
{
  const int wave = threadIdx.x >> 6;
  const int lane = threadIdx.x & 63;
  const long long row = (long long)blockIdx.x * 4 + wave;   // 0..32767
  const int q = (int)(row & 1023);
  const int b = (int)(row >> 13);
  unsigned short* Srow = S + row * 1024;
  const float* mrow = mask + ((size_t)b * 1024 + q) * 1024;

  u16x8 sv0 = ((const u16x8*)Srow)[lane * 2];
  u16x8 sv1 = ((const u16x8*)Srow)[lane * 2 + 1];
  float mk[16];
  const float4* m4 = (const float4*)mrow + lane * 4;
#pragma unroll
  for (int t = 0; t < 4; ++t) {
    float4 v = m4[t];
    mk[t * 4 + 0] = v.x; mk[t * 4 + 1] = v.y; mk[t * 4 + 2] = v.z; mk[t * 4 + 3] = v.w;
  }

  float lg[16];
#pragma unroll
  for (int j = 0; j < 8; ++j) lg[j] = bf2f(sv0[j]) - mk[j];
#pragma unroll
  for (int j = 0; j < 8; ++j) lg[8 + j] = bf2f(sv1[j]) - mk[8 + j];

  float mx = lg[0];
#pragma unroll
  for (int j = 1; j < 16; ++j) mx = fmaxf(mx, lg[j]);
#pragma unroll
  for (int off = 32; off > 0; off >>= 1) mx = fmaxf(mx, __shfl_xor(mx, off));

  float ex[16], sm = 0.f;
#pragma unroll
  for (int j = 0; j < 16; ++j) { ex[j] = __expf(lg[j] - mx); sm += ex[j]; }
#pragma unroll
  for (int off = 32; off > 0; off >>= 1) sm += __shfl_xor(sm, off);
  const float rinv = 1.0f / sm;

  u16x8 o0, o1;
#pragma unroll
  for (int j = 0; j < 8; ++j) o0[j] = f2bf(ex[j] * rinv);
#pragma unroll
  for (int j = 0; j < 8; ++j) o1[j] = f2bf(ex[8 + j] * rinv);
  ((u16x8*)Srow)[lane * 2] = o0;
  ((u16x8*)Srow)[lane * 2 + 1] = o1;
}

extern "C" void kernel_launch(void* const* d_in, const int* in_sizes, int n_in,
                              void* d_out, int out_size, void* d_ws, size_t ws_size,
                              hipStream_t stream) {
  const float* x    = (const float*)d_in[0];
  const float* mask = (const float*)d_in[1];
  const float* Wk   = (const float*)d_in[2];
  const float* Wq   = (const float*)d_in[3];
  const float* Wv   = (const float*)d_in[4];
  const float* Wu   = (const float*)d_in[5];
  const float* bu   = (const float*)d_in[6];

  const size_t MB = 1024 * 1024;
  if (ws_size < 212 * MB) return;
  char* ws = (char*)d_ws;
  unsigned short* xb  = (unsigned short*)(ws + 0 * MB);    // 4MB  [4096,512]
  unsigned short* Wqb = (unsigned short*)(ws + 4 * MB);
  unsigned short* Wkb = (unsigned short*)(ws + 8 * MB);
  unsigned short* Wvb = (unsigned short*)(ws + 12 * MB);
  unsigned short* Wub = (unsigned short*)(ws + 16 * MB);
  unsigned short* Qb  = (unsigned short*)(ws + 20 * MB);   // 32MB [b,t,h,e]
  unsigned short* Kb  = (unsigned short*)(ws + 52 * MB);   // 32MB
  unsigned short* Vt  = (unsigned short*)(ws + 84 * MB);   // 32MB [h*e, b*t]
  unsigned short* Sb  = (unsigned short*)(ws + 116 * MB);  // 64MB [b,h,q,k]
  unsigned short* Ob  = (unsigned short*)(ws + 180 * MB);  // 32MB [b,t,h*e]
  float* Pk = (float*)(ws + 20 * MB);  // split-K partials overlay Qb/Kb (dead post-attn)

  cast5_kernel<<<5 * 2048, 256, 0, stream>>>(x, Wq, Wk, Wv, Wu, xb);

  // Q and K projections fused: z=0 -> Wqb/Qb, z=1 -> Wkb/Kb
  gemm_bt2<unsigned short><<<dim3(32, 16, 2), 512, 0, stream>>>(
      xb, Wqb, Qb, 512, 512, 512, 4096, 0,
      0, 0, 2097152LL, 0, 16777216LL, 0, 1.0f);
  // Vt = Wv.x^T
  gemm_bt2<unsigned short><<<dim3(32, 16, 1), 512, 0, stream>>>(
      Wvb, xb, Vt, 512, 512, 512, 4096, 0, 0, 0, 0, 0, 0, 0, 1.0f);

  // S = (1/sqrt(512)) * Q.K^T per (b,h)   (M=N=1024, K=512, 32 batches)
  gemm_bt2<unsigned short><<<dim3(8, 4, 32), 512, 0, stream>>>(
      Qb, Kb, Sb, 512, 4096, 4096, 1024, 3,
      4194304LL, 512LL, 4194304LL, 512LL, 8388608LL, 1048576LL,
      0.044194173824159216f);

  // P = softmax(S - mask) in place
  softmax_kernel<<<8192, 256, 0, stream>>>(Sb, mask);

  // O = P.V   (M=1024, N=512, K=1024, 32 batches)
  gemm_bt2<unsigned short><<<dim3(4, 4, 32), 512, 0, stream>>>(
      Sb, Vt, Ob, 1024, 1024, 4096, 4096, 3,
      8388608LL, 1048576LL, 1024LL, 2097152LL, 4194304LL, 512LL, 1.0f);

  // out partials: split-K=8 over K=4096 (M=4096, N=512, slice=512)
  gemm_bt2<float><<<dim3(4, 16, 8), 512, 0, stream>>>(
      Ob, Wub, Pk, 512, 4096, 4096, 512, 0,
      512LL, 0, 512LL, 0, 2097152LL, 0, 1.0f);

  // out = sum_z Pk[z] + bu
  reduce_kernel<<<2048, 256, 0, stream>>>(Pk, bu, (float*)d_out);
}

// Round 16
// 250.162 us; speedup vs baseline: 1.1199x; 1.1199x over previous
//
#include <hip/hip_runtime.h>
#include <hip/hip_bf16.h>

// B=4, T=1024, E=512, H=8. Two-pass attention, all matmuls on one GEMM:
//   cast5 -> {QK proj + Vt} one dispatch -> S=QK^T*a -> softmax(S-mask)
//   -> O=P.V -> out GEMM split-K=8 + reduce(+bias).
// gemm_bt2 (R12-proven, best stable 250us): C = alpha*A.B^T, 256x256 tile,
// BK=32, 512 thr / 8 waves (2M x 4N), 3-buffer LDS (3x32KB=96KB), counted
// vmcnt pipeline: stage(t+2) each iter, s_waitcnt vmcnt(3..4) before raw
// s_barrier (t+1 forced complete, t+2 in flight). T5 setprio around MFMA.
// T1 bijective XCD swizzle (all grids % 8 == 0).
// vtSel: batch index hh==vtSel uses swapped pointers (A2,B2,C2) -- lets the
// Vt = Wv.x^T GEMM ride in the same dispatch as Q/K projections.
// MEASURED LAWS (R5-R15): (512,1) -> no spill (~100-116 VGPR + 128 acc AGPR);
// higher 2nd arg spills acc (WRITE_SIZE balloons). Fragment-major LDS =
// conflict-free ds_read_b128 (SQ_LDS_BANK_CONFLICT=0). Throughput pins at
// ~550 TF across BK/buffers/phases/occupancy = 2-phase structural ceiling
// (m233); 8-phase+T2 combo is the only documented escape (not reproduced).
// Layouts: Q,K [b,t,h,e] ld 4096; Vt [h*e, b*t]; S/P [b,h,q,k]; O [b,t,h*e].

typedef short bf16x8 __attribute__((ext_vector_type(8)));
typedef float f32x4 __attribute__((ext_vector_type(4)));
typedef unsigned short u16x8 __attribute__((ext_vector_type(8)));

__device__ __forceinline__ unsigned short f2bf(float f) {
  unsigned int u = __float_as_uint(f);
  u += 0x7FFFu + ((u >> 16) & 1u);            // RNE, finite inputs
  return (unsigned short)(u >> 16);
}
__device__ __forceinline__ float bf2f(unsigned short s) {
  return __uint_as_float(((unsigned int)s) << 16);
}

typedef const __attribute__((address_space(1))) unsigned int* gas1_t;
typedef __attribute__((address_space(3))) unsigned int* las3_t;

__device__ __forceinline__ void gload16(const unsigned short* g, unsigned short* l) {
  __builtin_amdgcn_global_load_lds((gas1_t)g, (las3_t)l, 16, 0, 0);
}

__device__ __forceinline__ void store_val(unsigned short* p, float v) { *p = f2bf(v); }
__device__ __forceinline__ void store_val(float* p, float v) { *p = v; }

// ---------------- 256x256-tile BT GEMM, BK=32, 3-buf counted-vmcnt ----------------
// Fragment-major LDS: frag f (f=0..15) holds tile rows f*16+l15, k-chunk lhi*8,
// slot=lane (16B). Buffer p at elems [p*16384,+16384): A [0,8192) B [8192,16384).
template<typename OutT>
__global__ __launch_bounds__(512, 1) void gemm_bt2(
    const unsigned short* __restrict__ A, const unsigned short* __restrict__ B,
    OutT* __restrict__ C,
    const unsigned short* __restrict__ A2, const unsigned short* __restrict__ B2,
    OutT* __restrict__ C2, int vtSel,
    int K, int lda, int ldb, int ldc, int zshift,
    long long sAb, long long sAh, long long sBb, long long sBh,
    long long sCb, long long sCh, float alpha)
{
  const int tid  = threadIdx.x;
  const int lane = tid & 63;
  const int wave = tid >> 6;
  const int l15 = lane & 15, lhi = lane >> 4;
  const int wm = wave >> 2, wn = wave & 3;           // 2M x 4N wave grid

  // T1: bijective XCD chunk swizzle (nwg % 8 == 0 for every launch here)
  const int nx = gridDim.x, nxy = gridDim.x * gridDim.y;
  const int nwg = nxy * gridDim.z;
  int flat = blockIdx.x + nx * blockIdx.y + nxy * blockIdx.z;
  flat = (flat & 7) * (nwg >> 3) + (flat >> 3);
  const int bz = flat / nxy;
  const int rem = flat - bz * nxy;
  const int by = rem / nx;
  const int bx = rem - by * nx;

  const int bb = bz >> zshift, hh = bz & ((1 << zshift) - 1);
  const long long m0 = (long long)by * 256;
  const long long n0 = (long long)bx * 256;

  const unsigned short* Ab;
  const unsigned short* Bb;
  OutT* Cb;
  if (hh == vtSel) { Ab = A2; Bb = B2; Cb = C2; }
  else {
    Ab = A + bb * sAb + hh * sAh;
    Bb = B + bb * sBb + hh * sBh;
    Cb = C + bb * sCb + hh * sCh;
  }

  __shared__ __align__(16) unsigned short lds[49152];  // 96 KB, 3 buffers

  // per-wave staging sources: 2 A-frags + 2 B-frags per K-step (frag f=c*8+wave)
  const unsigned short* gA[2];
  const unsigned short* gB[2];
  int fidx[2];
#pragma unroll
  for (int c = 0; c < 2; ++c) {
    const int f = c * 8 + wave;
    fidx[c] = f;
    gA[c] = Ab + (size_t)(m0 + f * 16 + l15) * lda + lhi * 8;
    gB[c] = Bb + (size_t)(n0 + f * 16 + l15) * ldb + lhi * 8;
  }

  // stage K-step n into buffer p (4 gload16 per wave, 32 KB per block)
  auto stage = [&](int n, int p) {
    unsigned short* dst = lds + p * 16384;
    const int ko = n * 32;
#pragma unroll
    for (int c = 0; c < 2; ++c) {
      gload16(gA[c] + ko, dst + fidx[c] * 512);
      gload16(gB[c] + ko, dst + 8192 + fidx[c] * 512);
    }
  };

  f32x4 acc[8][4];
#pragma unroll
  for (int m = 0; m < 8; ++m)
#pragma unroll
    for (int n = 0; n < 4; ++n) acc[m][n] = (f32x4){0.f, 0.f, 0.f, 0.f};

  const int nt = K >> 5;                // K-steps of 32
  // prologue: 2-deep prefetch
  stage(0, 0);
  stage(1, 1);
  asm volatile("s_waitcnt vmcnt(4)" ::: "memory");   // tile 0 landed
  __builtin_amdgcn_sched_barrier(0);
  __builtin_amdgcn_s_barrier();

  for (int t = 0; t < nt; ++t) {
    const bool pref = (t + 2 < nt);
    if (pref) stage(t + 2, (t + 2) % 3);             // stays in flight past barrier
    const unsigned short* base = lds + (t % 3) * 16384;
    bf16x8 af[8], bf[4];
#pragma unroll
    for (int mf = 0; mf < 8; ++mf)
      af[mf] = *(const bf16x8*)(base + (wm * 8 + mf) * 512 + lane * 8);
#pragma unroll
    for (int nf = 0; nf < 4; ++nf)
      bf[nf] = *(const bf16x8*)(base + 8192 + (wn * 4 + nf) * 512 + lane * 8);
    __builtin_amdgcn_s_setprio(1);
#pragma unroll
    for (int mf = 0; mf < 8; ++mf)
#pragma unroll
      for (int nf = 0; nf < 4; ++nf)
        acc[mf][nf] = __builtin_amdgcn_mfma_f32_16x16x32_bf16(af[mf], bf[nf], acc[mf][nf], 0, 0, 0);
    __builtin_amdgcn_s_setprio(0);
    // T4: counted drain -- only force tile t+1 complete; t+2 stays in flight
    if (pref) asm volatile("s_waitcnt vmcnt(4)" ::: "memory");
    else      asm volatile("s_waitcnt vmcnt(0)" ::: "memory");
    __builtin_amdgcn_sched_barrier(0);
    __builtin_amdgcn_s_barrier();
    __builtin_amdgcn_sched_barrier(0);               // pin ds_reads after barrier
  }

  // C/D layout (m89/m91): col = lane&15, row = (lane>>4)*4 + reg
#pragma unroll
  for (int mf = 0; mf < 8; ++mf) {
#pragma unroll
    for (int nf = 0; nf < 4; ++nf) {
      const long long col = n0 + wn * 64 + nf * 16 + l15;
#pragma unroll
      for (int r = 0; r < 4; ++r) {
        const long long row = m0 + wm * 128 + mf * 16 + lhi * 4 + r;
        store_val(Cb + (size_t)row * ldc + col, acc[mf][nf][r] * alpha);
      }
    }
  }
}

// ---------------- split-K reduce: out = sum(partials) + bias ----------------
__global__ __launch_bounds__(256) void reduce_kernel(
    const float* __restrict__ P, const float* __restrict__ bias,
    float* __restrict__ out)
{
  const int i = blockIdx.x * 256 + threadIdx.x;      // 0..524287 float4s
  const int col4 = i & 127;
  const float4* p4 = (const float4*)P + i;
  float4 s = p4[0];
#pragma unroll
  for (int z = 1; z < 8; ++z) {
    float4 v = p4[(size_t)z * 524288];
    s.x += v.x; s.y += v.y; s.z += v.z; s.w += v.w;
  }
  float4 b = ((const float4*)bias)[col4];
  s.x += b.x; s.y += b.y; s.z += b.z; s.w += b.w;
  ((float4*)out)[i] = s;
}

// ---------------- fused fp32 -> bf16 cast of all 5 tensors ----------------
__global__ __launch_bounds__(256) void cast5_kernel(
    const float* __restrict__ s0, const float* __restrict__ s1,
    const float* __restrict__ s2, const float* __restrict__ s3,
    const float* __restrict__ s4, unsigned short* __restrict__ dst)
{
  const int seg = blockIdx.x >> 11;
  const int off = (blockIdx.x & 2047) * 256 + threadIdx.x;
  const float* s = s0;
  if (seg == 1) s = s1; else if (seg == 2) s = s2;
  else if (seg == 3) s = s3; else if (seg == 4) s = s4;
  float4 v = ((const float4*)s)[off];
  ushort4 o;
  o.x = f2bf(v.x); o.y = f2bf(v.y); o.z = f2bf(v.z); o.w = f2bf(v.w);
  ((ushort4*)dst)[(size_t)seg * 524288 + off] = o;
}

// ---------------- in-place row softmax over S (bf16), logit = S - mask ----------------
__global__ __launch_bounds__(256) void softmax_kernel(
    unsigned short* __restrict__ S, const float* __restrict__ mask)
{
  const int wave = threadIdx.x >> 6;
  const int lane = threadIdx.x & 63;
  const long long row = (long long)blockIdx.x * 4 + wave;   // 0..32767
  const int q = (int)(row & 1023);
  const int b = (int)(row >> 13);
  unsigned short* Srow = S + row * 1024;
  const float* mrow = mask + ((size_t)b * 1024 + q) * 1024;

  u16x8 sv0 = ((const u16x8*)Srow)[lane * 2];
  u16x8 sv1 = ((const u16x8*)Srow)[lane * 2 + 1];
  float mk[16];
  const float4* m4 = (const float4*)mrow + lane * 4;
#pragma unroll
  for (int t = 0; t < 4; ++t) {
    float4 v = m4[t];
    mk[t * 4 + 0] = v.x; mk[t * 4 + 1] = v.y; mk[t * 4 + 2] = v.z; mk[t * 4 + 3] = v.w;
  }

  float lg[16];
#pragma unroll
  for (int j = 0; j < 8; ++j) lg[j] = bf2f(sv0[j]) - mk[j];
#pragma unroll
  for (int j = 0; j < 8; ++j) lg[8 + j] = bf2f(sv1[j]) - mk[8 + j];

  float mx = lg[0];
#pragma unroll
  for (int j = 1; j < 16; ++j) mx = fmaxf(mx, lg[j]);
#pragma unroll
  for (int off = 32; off > 0; off >>= 1) mx = fmaxf(mx, __shfl_xor(mx, off));

  float ex[16], sm = 0.f;
#pragma unroll
  for (int j = 0; j < 16; ++j) { ex[j] = __expf(lg[j] - mx); sm += ex[j]; }
#pragma unroll
  for (int off = 32; off > 0; off >>= 1) sm += __shfl_xor(sm, off);
  const float rinv = 1.0f / sm;

  u16x8 o0, o1;
#pragma unroll
  for (int j = 0; j < 8; ++j) o0[j] = f2bf(ex[j] * rinv);
#pragma unroll
  for (int j = 0; j < 8; ++j) o1[j] = f2bf(ex[8 + j] * rinv);
  ((u16x8*)Srow)[lane * 2] = o0;
  ((u16x8*)Srow)[lane * 2 + 1] = o1;
}

extern "C" void kernel_launch(void* const* d_in, const int* in_sizes, int n_in,
                              void* d_out, int out_size, void* d_ws, size_t ws_size,
                              hipStream_t stream) {
  const float* x    = (const float*)d_in[0];
  const float* mask = (const float*)d_in[1];
  const float* Wk   = (const float*)d_in[2];
  const float* Wq   = (const float*)d_in[3];
  const float* Wv   = (const float*)d_in[4];
  const float* Wu   = (const float*)d_in[5];
  const float* bu   = (const float*)d_in[6];

  const size_t MB = 1024 * 1024;
  if (ws_size < 212 * MB) return;
  char* ws = (char*)d_ws;
  unsigned short* xb  = (unsigned short*)(ws + 0 * MB);    // 4MB  [4096,512]
  unsigned short* Wqb = (unsigned short*)(ws + 4 * MB);
  unsigned short* Wkb = (unsigned short*)(ws + 8 * MB);
  unsigned short* Wvb = (unsigned short*)(ws + 12 * MB);
  unsigned short* Wub = (unsigned short*)(ws + 16 * MB);
  unsigned short* Qb  = (unsigned short*)(ws + 20 * MB);   // 32MB [b,t,h,e]
  unsigned short* Kb  = (unsigned short*)(ws + 52 * MB);   // 32MB
  unsigned short* Vt  = (unsigned short*)(ws + 84 * MB);   // 32MB [h*e, b*t]
  unsigned short* Sb  = (unsigned short*)(ws + 116 * MB);  // 64MB [b,h,q,k]
  unsigned short* Ob  = (unsigned short*)(ws + 180 * MB);  // 32MB [b,t,h*e]
  float* Pk = (float*)(ws + 20 * MB);  // split-K partials overlay Qb/Kb (dead post-attn)

  cast5_kernel<<<5 * 2048, 256, 0, stream>>>(x, Wq, Wk, Wv, Wu, xb);

  // Q proj (hh=0), K proj (hh=1), Vt = Wv.x^T (hh=2 via vtSel pointer swap)
  // nwg = 16*16*3 = 768, % 8 == 0 (T1 bijective)
  gemm_bt2<unsigned short><<<dim3(16, 16, 3), 512, 0, stream>>>(
      xb, Wqb, Qb, Wvb, xb, Vt, 2,
      512, 512, 512, 4096, 2,
      0, 0, 0, 2097152LL, 0, 16777216LL, 1.0f);

  // S = (1/sqrt(512)) * Q.K^T per (b,h)   (M=N=1024, K=512, 32 batches)
  gemm_bt2<unsigned short><<<dim3(4, 4, 32), 512, 0, stream>>>(
      Qb, Kb, Sb, nullptr, nullptr, nullptr, -1,
      512, 4096, 4096, 1024, 3,
      4194304LL, 512LL, 4194304LL, 512LL, 8388608LL, 1048576LL,
      0.044194173824159216f);

  // P = softmax(S - mask) in place
  softmax_kernel<<<8192, 256, 0, stream>>>(Sb, mask);

  // O = P.V   (M=1024, N=512, K=1024, 32 batches)
  gemm_bt2<unsigned short><<<dim3(2, 4, 32), 512, 0, stream>>>(
      Sb, Vt, Ob, nullptr, nullptr, nullptr, -1,
      1024, 1024, 4096, 4096, 3,
      8388608LL, 1048576LL, 1024LL, 2097152LL, 4194304LL, 512LL, 1.0f);

  // out partials: split-K=8 over K=4096 (M=4096, N=512, slice=512)
  gemm_bt2<float><<<dim3(2, 16, 8), 512, 0, stream>>>(
      Ob, Wub, Pk, nullptr, nullptr, nullptr, -1,
      512, 4096, 4096, 512, 0,
      512LL, 0, 512LL, 0, 2097152LL, 0, 1.0f);

  // out = sum_z Pk[z] + bu
  reduce_kernel<<<2048, 256, 0, stream>>>(Pk, bu, (float*)d_out);
}